// Round 1
// baseline (2060.611 us; speedup 1.0000x reference)
//
#include <hip/hip_runtime.h>

// Projector: out[to[i]] += x[from[i]]  (gather + segment-sum)
// x: [524288, 128] f32, from/to: [1048576] int, out: [262144, 128] f32

#define NNZ      1048576
#define D        128
#define NUM_TO   262144

// 32 threads per edge; each thread handles 4 contiguous features (float4).
__global__ __launch_bounds__(256)
void projector_scatter_add(const float* __restrict__ x,
                           const int*   __restrict__ from_idx,
                           const int*   __restrict__ to_idx,
                           float*       __restrict__ out) {
    const int tid  = blockIdx.x * blockDim.x + threadIdx.x;
    const int edge = tid >> 5;   // 32 threads per edge
    const int fg   = tid & 31;   // feature group (4 floats each)
    if (edge >= NNZ) return;

    const int f = from_idx[edge];
    const int t = to_idx[edge];

    const float4 v = *reinterpret_cast<const float4*>(
        x + (size_t)f * D + (size_t)fg * 4);
    float* o = out + (size_t)t * D + (size_t)fg * 4;

    atomicAdd(o + 0, v.x);
    atomicAdd(o + 1, v.y);
    atomicAdd(o + 2, v.z);
    atomicAdd(o + 3, v.w);
}

extern "C" void kernel_launch(void* const* d_in, const int* in_sizes, int n_in,
                              void* d_out, int out_size, void* d_ws, size_t ws_size,
                              hipStream_t stream) {
    const float* x        = (const float*)d_in[0];
    const int*   from_idx = (const int*)  d_in[1];
    const int*   to_idx   = (const int*)  d_in[2];
    float*       out      = (float*)      d_out;

    // out is re-poisoned to 0xAA before every timed launch — zero it.
    hipMemsetAsync(d_out, 0, (size_t)out_size * sizeof(float), stream);

    const int threads_total = NNZ * 32;           // 32 threads per edge
    const int block = 256;
    const int grid  = (threads_total + block - 1) / block;  // 131072 blocks
    projector_scatter_add<<<grid, block, 0, stream>>>(x, from_idx, to_idx, out);
}